// Round 6
// baseline (615.546 us; speedup 1.0000x reference)
//
#include <hip/hip_runtime.h>
#include <math.h>

// MACE-like block. CSR-sorted edges + f16 MFMA R-GEMM fused with aggregation.
// R6: species-sorted node batching (2 same-species nodes/wave, weight-register
//     reuse) + [c][m]-transposed LDS activations (broadcast float4 reads).
// N=10000 nodes, E=160000 edges, C=64, 16 sph, S=10 species.

typedef _Float16 half8 __attribute__((ext_vector_type(8)));
typedef float f32x4 __attribute__((ext_vector_type(4)));

__device__ __forceinline__ float silu_f(float x) { return x / (1.0f + expf(-x)); }

__device__ __forceinline__ float reduce64(float v) {
#pragma unroll
  for (int off = 32; off > 0; off >>= 1) v += __shfl_xor(v, off, 64);
  return v;
}

__device__ __forceinline__ void compute_Y(float x, float y, float z, float* Y) {
  float x2 = x * x, y2 = y * y, z2 = z * z;
  Y[0] = 1.0f;
  Y[1] = 1.7320508f * x;
  Y[2] = 1.7320508f * y;
  Y[3] = 1.7320508f * z;
  Y[4] = 3.8729833f * x * y;
  Y[5] = 3.8729833f * y * z;
  Y[6] = 1.118034f * (3.0f * z2 - 1.0f);
  Y[7] = 3.8729833f * x * z;
  Y[8] = 1.9364917f * (x2 - y2);
  Y[9] = 2.09165f * y * (3.0f * x2 - y2);
  Y[10] = 10.246951f * x * y * z;
  Y[11] = 1.6201852f * y * (5.0f * z2 - 1.0f);
  Y[12] = 1.3228757f * z * (5.0f * z2 - 3.0f);
  Y[13] = 1.6201852f * x * (5.0f * z2 - 1.0f);
  Y[14] = 5.1234753f * z * (x2 - y2);
  Y[15] = 2.09165f * x * (x2 - 3.0f * y2);
}

__device__ __forceinline__ void compute_rb(float r, float inv_r, float* rb) {
  float t = fminf(r * 0.2f, 1.0f);
  float t2 = t * t;
  float t5 = t2 * t2 * t;
  float env = 1.0f + t5 * (-21.0f + t * (35.0f - 15.0f * t));
  float th = 0.62831853f * r;  // pi*r/5
  float s1 = sinf(th), c1 = cosf(th);
  float c2 = 2.0f * c1;
  float sprev = 0.0f, scur = s1;
  float coef = 0.63245553f * inv_r * env;
#pragma unroll
  for (int k = 0; k < 8; k++) {
    rb[k] = coef * scur;
    float snxt = c2 * scur - sprev;
    sprev = scur; scur = snxt;
  }
}

// 16 FMAs against the l-grouped weight columns; Ab is [c][16] LDS (broadcast).
__device__ __forceinline__ void fma16(float* fr, const float* Ab, int c,
                                      float w0, float w1, float w2, float w3) {
  float4 a0 = *(const float4*)(Ab + c * 16);
  float4 a1 = *(const float4*)(Ab + c * 16 + 4);
  float4 a2 = *(const float4*)(Ab + c * 16 + 8);
  float4 a3 = *(const float4*)(Ab + c * 16 + 12);
  fr[0] += a0.x * w0;
  fr[1] += a0.y * w1;  fr[2] += a0.z * w1;  fr[3] += a0.w * w1;
  fr[4] += a1.x * w2;  fr[5] += a1.y * w2;  fr[6] += a1.z * w2;
  fr[7] += a1.w * w2;  fr[8] += a2.x * w2;
  fr[9] += a2.y * w3;  fr[10] += a2.z * w3; fr[11] += a2.w * w3;
  fr[12] += a3.x * w3; fr[13] += a3.y * w3; fr[14] += a3.z * w3;
  fr[15] += a3.w * w3;
}

// ---------------------------------------------------------------- CSR build (edges)
__global__ __launch_bounds__(256) void k_hist(const int* __restrict__ receivers,
                                              int* __restrict__ cnt, int E) {
  int e = blockIdx.x * 256 + threadIdx.x;
  if (e < E) atomicAdd(&cnt[receivers[e]], 1);
}

__global__ __launch_bounds__(256) void k_scan(const int* __restrict__ deg,
                                              int* __restrict__ row_start,
                                              int* __restrict__ cursor, int N) {
  __shared__ int part[256];
  int t = threadIdx.x;
  int K = (N + 255) / 256;
  int lo = t * K, hi = min(lo + K, N);
  int s = 0;
  for (int i = lo; i < hi; i++) s += deg[i];
  part[t] = s;
  __syncthreads();
  for (int d = 1; d < 256; d <<= 1) {
    int v = (t >= d) ? part[t - d] : 0;
    __syncthreads();
    part[t] += v;
    __syncthreads();
  }
  int run = (t == 0) ? 0 : part[t - 1];
  for (int i = lo; i < hi; i++) {
    int di = deg[i];            // deg aliases cursor; read before overwrite
    row_start[i] = run;
    cursor[i] = run;
    run += di;
  }
  if (t == 255) row_start[N] = part[255];
}

__global__ __launch_bounds__(256) void k_scatter(const int* __restrict__ receivers,
                                                 const int* __restrict__ senders,
                                                 int* __restrict__ cursor,
                                                 int* __restrict__ perm,
                                                 int* __restrict__ rsort,
                                                 int* __restrict__ ssort, int E) {
  int e = blockIdx.x * 256 + threadIdx.x;
  if (e < E) {
    int r = receivers[e];
    int pos = atomicAdd(&cursor[r], 1);
    perm[pos] = e;
    rsort[pos] = r;
    ssort[pos] = senders[e];
  }
}

// ---------------------------------------------------------------- species sort (nodes)
__global__ __launch_bounds__(256) void k_nhist(const int* __restrict__ species,
                                               int* __restrict__ scnt, int N) {
  int n = blockIdx.x * 256 + threadIdx.x;
  if (n < N) atomicAdd(&scnt[species[n]], 1);
}

// single thread: padded (GROUP=8) starts; scnt becomes the running cursor.
__global__ void k_nscan(int* __restrict__ scnt) {
  int run = 0;
#pragma unroll
  for (int s = 0; s < 10; s++) {
    int c = scnt[s];
    scnt[s] = run;
    run += ((c + 7) / 8) * 8;
  }
}

__global__ __launch_bounds__(256) void k_nscatter(const int* __restrict__ species,
                                                  int* __restrict__ scnt,
                                                  int* __restrict__ nsort, int N) {
  int n = blockIdx.x * 256 + threadIdx.x;
  if (n < N) {
    int pos = atomicAdd(&scnt[species[n]], 1);
    nsort[pos] = n;
  }
}

// ---------------------------------------------------------------- pack rw2 -> f16 B^T
__global__ __launch_bounds__(256) void k_pack(const float* __restrict__ rw2,
                                              _Float16* __restrict__ b1t,
                                              _Float16* __restrict__ b2t) {
  int idx = blockIdx.x * 256 + threadIdx.x;
  if (idx < 16384) {
    int n = idx >> 6, k = idx & 63;
    int c = n >> 2, j = n & 3;
    b1t[idx] = (_Float16)rw2[k * 768 + c * 12 + j];
  } else if (idx < 40960) {
    int i2 = idx - 16384;
    int n = i2 >> 6, k = i2 & 63;
    int c = n / 6, j = n - c * 6;
    int col = (j < 4) ? j : ((j == 4) ? 5 : 9);
    b2t[i2] = (_Float16)rw2[49152 + k * 768 + c * 12 + col];
  }
}

// ---------------------------------------------------------------- up0
__global__ __launch_bounds__(256) void k_up0(const float* __restrict__ embed,
                                             const float* __restrict__ lu0,
                                             const int* __restrict__ species,
                                             float* __restrict__ up0, int N) {
  int wave = threadIdx.x >> 6, lane = threadIdx.x & 63;
  int n = (blockIdx.x << 2) + wave;
  if (n >= N) return;
  int sp = species[n];
  const float* er = embed + sp * 64;
  float acc = 0.0f;
#pragma unroll 8
  for (int c = 0; c < 64; c++) acc += er[c] * lu0[c * 64 + lane];
  up0[(size_t)n * 64 + lane] = acc;
}

// ---------------------------------------------------------------- geometry (sorted order)
__global__ __launch_bounds__(256) void k_geom(const float* __restrict__ ev,
                                              const float* __restrict__ rw1,
                                              const int* __restrict__ perm,
                                              _Float16* __restrict__ hid0,
                                              _Float16* __restrict__ hid1,
                                              float* __restrict__ Ysort,
                                              int* __restrict__ rsort,
                                              int* __restrict__ ssort,
                                              int E, int EPAD) {
  int wave = threadIdx.x >> 6, lane = threadIdx.x & 63;
  int j = blockIdx.x * 4 + wave;
  if (j >= EPAD) return;
  if (j >= E) {
    hid0[(size_t)j * 64 + lane] = (_Float16)0.0f;
    hid1[(size_t)j * 64 + lane] = (_Float16)0.0f;
    if (lane == 0) { rsort[j] = -1; ssort[j] = 0; }
    if (lane < 16) Ysort[(size_t)j * 16 + lane] = 0.0f;
    return;
  }
  int e = perm[j];
  float vx = ev[e * 3 + 0], vy = ev[e * 3 + 1], vz = ev[e * 3 + 2];
  float r = sqrtf(vx * vx + vy * vy + vz * vz);
  float inv_r = 1.0f / (r + 1e-8f);
  float Y[16]; compute_Y(vx * inv_r, vy * inv_r, vz * inv_r, Y);
  float rb[8]; compute_rb(r, inv_r, rb);

  float h0 = 0.0f, h1 = 0.0f;
#pragma unroll
  for (int k = 0; k < 8; k++) {
    h0 += rb[k] * rw1[k * 64 + lane];
    h1 += rb[k] * rw1[512 + k * 64 + lane];
  }
  hid0[(size_t)j * 64 + lane] = (_Float16)silu_f(h0);
  hid1[(size_t)j * 64 + lane] = (_Float16)silu_f(h1);

  float yv = Y[0];
#pragma unroll
  for (int m = 1; m < 16; m++) yv = (lane == m) ? Y[m] : yv;
  if (lane < 16) Ysort[(size_t)j * 16 + lane] = yv;
}

// ---------------------------------------------------------------- fused MFMA + agg, pass 1
__global__ __launch_bounds__(256) void k_fagg1(const _Float16* __restrict__ hid,
                                               const _Float16* __restrict__ bt,
                                               const float* __restrict__ Ysort,
                                               const float* __restrict__ up0,
                                               const int* __restrict__ ssort,
                                               const int* __restrict__ rsort,
                                               float* __restrict__ agg, int E) {
  __shared__ _Float16 __attribute__((aligned(16))) lds[4][16 * 256];  // 32 KB
  int wave = threadIdx.x >> 6, lane = threadIdx.x & 63;
  int q = lane >> 4, mr = lane & 15;
  _Float16* L = lds[wave];
  int j0 = __builtin_amdgcn_readfirstlane((blockIdx.x * 4 + wave) * 16);

  int rs[16], ss[16];
#pragma unroll
  for (int t = 0; t < 16; t++) {
    rs[t] = rsort[j0 + t];
    ss[t] = ssort[j0 + t];
  }
  float hsv[16];
#pragma unroll
  for (int t = 0; t < 16; t++)
    hsv[t] = up0[((size_t)ss[t] << 6) + lane];

  const half8* Ap = (const half8*)(hid + (size_t)(j0 + mr) * 64 + q * 8);
  half8 a0 = Ap[0];
  half8 a1 = Ap[4];
  const _Float16* bp = bt + (size_t)mr * 64 + q * 8;
#pragma unroll
  for (int T = 0; T < 16; T++) {
    half8 b0 = *(const half8*)(bp + T * 1024);
    half8 b1 = *(const half8*)(bp + T * 1024 + 32);
    f32x4 acc = {0.f, 0.f, 0.f, 0.f};
    acc = __builtin_amdgcn_mfma_f32_16x16x32_f16(a0, b0, acc, 0, 0, 0);
    acc = __builtin_amdgcn_mfma_f32_16x16x32_f16(a1, b1, acc, 0, 0, 0);
#pragma unroll
    for (int r = 0; r < 4; r++)
      L[(q * 4 + r) * 256 + T * 16 + mr] = (_Float16)acc[r];
  }

  float accm[16];
#pragma unroll
  for (int m = 0; m < 16; m++) accm[m] = 0.0f;
  int cur_r = (j0 < E) ? rs[0] : -1;

#pragma unroll
  for (int t = 0; t < 16; t++) {
    int j = j0 + t;
    bool ok = (j < E);
    int rr = ok ? rs[t] : -2;
    if (rr != cur_r) {
      if (cur_r >= 0) {
        float* base = agg + ((size_t)cur_r << 10) + lane;
#pragma unroll
        for (int m = 0; m < 16; m++) atomicAdd(base + (m << 6), accm[m]);
      }
#pragma unroll
      for (int m = 0; m < 16; m++) accm[m] = 0.0f;
      cur_r = rr;
    }
    if (ok) {
      float hs0 = hsv[t];
      const _Float16* Rr = L + t * 256 + lane * 4;
      float p0 = (float)Rr[0] * hs0, p1 = (float)Rr[1] * hs0;
      float p2 = (float)Rr[2] * hs0, p3 = (float)Rr[3] * hs0;
      const float* Yj = Ysort + (size_t)j * 16;
      float4 Ya = *(const float4*)(Yj);
      float4 Yb = *(const float4*)(Yj + 4);
      float4 Yc = *(const float4*)(Yj + 8);
      float4 Yd = *(const float4*)(Yj + 12);
      accm[0] += p0;
      accm[1] += p1 * Ya.y;  accm[2] += p1 * Ya.z;  accm[3] += p1 * Ya.w;
      accm[4] += p2 * Yb.x;  accm[5] += p2 * Yb.y;  accm[6] += p2 * Yb.z;
      accm[7] += p2 * Yb.w;  accm[8] += p2 * Yc.x;
      accm[9]  += p3 * Yc.y; accm[10] += p3 * Yc.z; accm[11] += p3 * Yc.w;
      accm[12] += p3 * Yd.x; accm[13] += p3 * Yd.y; accm[14] += p3 * Yd.z;
      accm[15] += p3 * Yd.w;
    }
  }
  if (cur_r >= 0) {
    float* base = agg + ((size_t)cur_r << 10) + lane;
#pragma unroll
    for (int m = 0; m < 16; m++) atomicAdd(base + (m << 6), accm[m]);
  }
}

// ---------------------------------------------------------------- fused MFMA + agg, pass 2
__global__ __launch_bounds__(256) void k_fagg2(const _Float16* __restrict__ hid,
                                               const _Float16* __restrict__ bt,
                                               const float* __restrict__ Ysort,
                                               const float* __restrict__ up1,
                                               const int* __restrict__ ssort,
                                               const int* __restrict__ rsort,
                                               float* __restrict__ agg, int E) {
  __shared__ _Float16 __attribute__((aligned(16))) lds[4][16 * 384];  // 48 KB
  int wave = threadIdx.x >> 6, lane = threadIdx.x & 63;
  int q = lane >> 4, mr = lane & 15;
  _Float16* L = lds[wave];
  int j0 = __builtin_amdgcn_readfirstlane((blockIdx.x * 4 + wave) * 16);

  int rs[16], ss[16];
#pragma unroll
  for (int t = 0; t < 16; t++) {
    rs[t] = rsort[j0 + t];
    ss[t] = ssort[j0 + t];
  }
  float4 hA[8];
#pragma unroll
  for (int t = 0; t < 8; t++)
    hA[t] = *(const float4*)(up1 + ((size_t)ss[t] << 8) + lane * 4);

  const half8* Ap = (const half8*)(hid + (size_t)(j0 + mr) * 64 + q * 8);
  half8 a0 = Ap[0];
  half8 a1 = Ap[4];
  const _Float16* bp = bt + (size_t)mr * 64 + q * 8;
#pragma unroll
  for (int T = 0; T < 24; T++) {
    half8 b0 = *(const half8*)(bp + T * 1024);
    half8 b1 = *(const half8*)(bp + T * 1024 + 32);
    f32x4 acc = {0.f, 0.f, 0.f, 0.f};
    acc = __builtin_amdgcn_mfma_f32_16x16x32_f16(a0, b0, acc, 0, 0, 0);
    acc = __builtin_amdgcn_mfma_f32_16x16x32_f16(a1, b1, acc, 0, 0, 0);
#pragma unroll
    for (int r = 0; r < 4; r++)
      L[(q * 4 + r) * 384 + T * 16 + mr] = (_Float16)acc[r];
  }

  float4 hB[8];
#pragma unroll
  for (int t = 0; t < 8; t++)
    hB[t] = *(const float4*)(up1 + ((size_t)ss[8 + t] << 8) + lane * 4);

  float accm[16];
#pragma unroll
  for (int m = 0; m < 16; m++) accm[m] = 0.0f;
  int cur_r = (j0 < E) ? rs[0] : -1;

#pragma unroll
  for (int t = 0; t < 16; t++) {
    int j = j0 + t;
    bool ok = (j < E);
    int rr = ok ? rs[t] : -2;
    if (rr != cur_r) {
      if (cur_r >= 0) {
        float* base = agg + ((size_t)cur_r << 10) + lane;
#pragma unroll
        for (int m = 0; m < 16; m++) atomicAdd(base + (m << 6), accm[m]);
      }
#pragma unroll
      for (int m = 0; m < 16; m++) accm[m] = 0.0f;
      cur_r = rr;
    }
    if (ok) {
      float4 hs = (t < 8) ? hA[t & 7] : hB[t & 7];
      float hs0 = hs.x, hs1 = hs.y, hs2 = hs.z, hs3 = hs.w;
      const _Float16* Rr = L + t * 384 + lane * 6;
      float R0 = (float)Rr[0], R1v = (float)Rr[1];
      float R2v = (float)Rr[2], R3v = (float)Rr[3];
      float c5 = (float)Rr[4], c9 = (float)Rr[5];
      float q0 = R0 * hs0, q1 = R1v * hs0, q2 = R2v * hs0, q3 = R3v * hs0;
      const float* Yj = Ysort + (size_t)j * 16;
      float4 Ya = *(const float4*)(Yj);
      float4 Yb = *(const float4*)(Yj + 4);
      float4 Yc = *(const float4*)(Yj + 8);
      float4 Yd = *(const float4*)(Yj + 12);
      accm[0] += q0 + c9 * (hs1 * Ya.y + hs2 * Ya.z + hs3 * Ya.w);
      accm[1] += q1 * Ya.y + c5 * hs1;
      accm[2] += q1 * Ya.z + c5 * hs2;
      accm[3] += q1 * Ya.w + c5 * hs3;
      accm[4] += q2 * Yb.x;  accm[5] += q2 * Yb.y;  accm[6] += q2 * Yb.z;
      accm[7] += q2 * Yb.w;  accm[8] += q2 * Yc.x;
      accm[9]  += q3 * Yc.y; accm[10] += q3 * Yc.z; accm[11] += q3 * Yc.w;
      accm[12] += q3 * Yd.x; accm[13] += q3 * Yd.y; accm[14] += q3 * Yd.z;
      accm[15] += q3 * Yd.w;
    }
  }
  if (cur_r >= 0) {
    float* base = agg + ((size_t)cur_r << 10) + lane;
#pragma unroll
    for (int m = 0; m < 16; m++) atomicAdd(base + (m << 6), accm[m]);
  }
}

// ---------------------------------------------------------------- node kernel 1
// 256 thr = 4 waves x 2 same-species nodes. Activations in LDS as [c][16]
// (broadcast float4 reads); weights loaded once per wave, reused for 2 nodes.
__global__ __launch_bounds__(256) void k_node1(float* __restrict__ agg0,
                                               const float* __restrict__ ld0,
                                               const float* __restrict__ sel_w,
                                               const float* __restrict__ pw0,
                                               const float* __restrict__ res_w,
                                               const float* __restrict__ lu1,
                                               const float* __restrict__ read0,
                                               const int* __restrict__ species,
                                               const int* __restrict__ nsort,
                                               float* __restrict__ out,
                                               float* __restrict__ res,
                                               float* __restrict__ up1) {
  __shared__ float __attribute__((aligned(16))) sm[4][2][2][1024];  // 64 KB
  int wave = threadIdx.x >> 6, d = threadIdx.x & 63;
  int i0 = blockIdx.x * 8 + wave * 2;
  int n0 = nsort[i0], n1 = nsort[i0 + 1];
  if (n0 < 0) return;            // padded tail (n1 also -1)
  bool ok1 = (n1 >= 0);
  int nv1 = ok1 ? n1 : n0;
  int sp = species[n0];
  float* A0 = sm[wave][0][0]; float* B0 = sm[wave][0][1];
  float* A1 = sm[wave][1][0]; float* B1 = sm[wave][1][1];

  // load agg (scaled) transposed to [c][m]; zero agg in place for fagg2
  {
    float* ag = agg0 + ((size_t)n0 << 10);
    float v[16];
#pragma unroll
    for (int m = 0; m < 16; m++) {
      v[m] = ag[(m << 6) + d] * 0.0625f;
      ag[(m << 6) + d] = 0.0f;
    }
#pragma unroll
    for (int g = 0; g < 4; g++)
      *(float4*)(A0 + d * 16 + g * 4) = make_float4(v[g*4], v[g*4+1], v[g*4+2], v[g*4+3]);
  }
  {
    float* ag = agg0 + ((size_t)nv1 << 10);
    float v[16];
#pragma unroll
    for (int m = 0; m < 16; m++) {
      v[m] = ag[(m << 6) + d] * 0.0625f;
      if (ok1) ag[(m << 6) + d] = 0.0f;
    }
#pragma unroll
    for (int g = 0; g < 4; g++)
      *(float4*)(A1 + d * 16 + g * 4) = make_float4(v[g*4], v[g*4+1], v[g*4+2], v[g*4+3]);
  }

  // stage A: fint = agg @ ld0[l]
  float fr0[16], fr1[16];
#pragma unroll
  for (int m = 0; m < 16; m++) { fr0[m] = 0.0f; fr1[m] = 0.0f; }
#pragma unroll 4
  for (int c = 0; c < 64; c++) {
    float w0 = ld0[c * 64 + d];
    float w1 = ld0[4096 + c * 64 + d];
    float w2 = ld0[8192 + c * 64 + d];
    float w3 = ld0[12288 + c * 64 + d];
    fma16(fr0, A0, c, w0, w1, w2, w3);
    fma16(fr1, A1, c, w0, w1, w2, w3);
  }
#pragma unroll
  for (int g = 0; g < 4; g++) {
    *(float4*)(B0 + d * 16 + g * 4) = make_float4(fr0[g*4], fr0[g*4+1], fr0[g*4+2], fr0[g*4+3]);
    *(float4*)(B1 + d * 16 + g * 4) = make_float4(fr1[g*4], fr1[g*4+1], fr1[g*4+2], fr1[g*4+3]);
  }

  // stage B: f = fint @ sel_w[sp][l]
  float f20[16], f21[16];
#pragma unroll
  for (int m = 0; m < 16; m++) { f20[m] = 0.0f; f21[m] = 0.0f; }
  const float* Ws = sel_w + ((size_t)(sp * 4) << 12);
#pragma unroll 4
  for (int c = 0; c < 64; c++) {
    float w0 = Ws[c * 64 + d];
    float w1 = Ws[4096 + c * 64 + d];
    float w2 = Ws[8192 + c * 64 + d];
    float w3 = Ws[12288 + c * 64 + d];
    fma16(f20, B0, c, w0, w1, w2, w3);
    fma16(f21, B1, c, w0, w1, w2, w3);
  }
  {
    float s0 = f20[0], tt = 1.0f + s0 + s0 * s0;
    *(float4*)(A0 + d * 16) = make_float4(f20[0]*tt, f20[1]*tt, f20[2]*tt, f20[3]*tt);
    float s1 = f21[0], tu = 1.0f + s1 + s1 * s1;
    *(float4*)(A1 + d * 16) = make_float4(f21[0]*tu, f21[1]*tu, f21[2]*tu, f21[3]*tu);
  }

  // stage C: f1 = tf @ prod_w0[sp], m<4
  float f10[4] = {0.f, 0.f, 0.f, 0.f}, f11[4] = {0.f, 0.f, 0.f, 0.f};
  const float* Wp = pw0 + ((size_t)sp << 12);
#pragma unroll 4
  for (int c = 0; c < 64; c++) {
    float w = Wp[c * 64 + d];
    float4 a0 = *(const float4*)(A0 + c * 16);
    float4 a1 = *(const float4*)(A1 + c * 16);
    f10[0] += a0.x * w; f10[1] += a0.y * w; f10[2] += a0.z * w; f10[3] += a0.w * w;
    f11[0] += a1.x * w; f11[1] += a1.y * w; f11[2] += a1.z * w; f11[3] += a1.w * w;
  }
  *(float4*)(B0 + d * 16) = make_float4(f10[0], f10[1], f10[2], f10[3]);
  *(float4*)(B1 + d * 16) = make_float4(f11[0], f11[1], f11[2], f11[3]);

  // out0 = f1[:,0] . read0
  float rd = read0[d];
  float v0 = reduce64(f10[0] * rd);
  float v1 = reduce64(f11[0] * rd);
  if (d == 0) {
    out[2 * n0] = v0;
    if (ok1) out[2 * n1] = v1;
  }

  // res = f1[:,0] @ res_w[sp]; up1 (layout [n][d][4]) via lu1[0], lu1[1]
  float r0 = 0.f, u00 = 0.f, u01 = 0.f, u02 = 0.f, u03 = 0.f;
  float r1 = 0.f, u10 = 0.f, u11 = 0.f, u12 = 0.f, u13 = 0.f;
  const float* Wr = res_w + ((size_t)sp << 12);
#pragma unroll 4
  for (int c = 0; c < 64; c++) {
    float wr = Wr[c * 64 + d];
    float wu0 = lu1[c * 64 + d];
    float wu1 = lu1[4096 + c * 64 + d];
    float4 a0 = *(const float4*)(B0 + c * 16);
    float4 a1 = *(const float4*)(B1 + c * 16);
    r0 += a0.x * wr;  u00 += a0.x * wu0;
    u01 += a0.y * wu1; u02 += a0.z * wu1; u03 += a0.w * wu1;
    r1 += a1.x * wr;  u10 += a1.x * wu0;
    u11 += a1.y * wu1; u12 += a1.z * wu1; u13 += a1.w * wu1;
  }
  res[((size_t)n0 << 6) + d] = r0;
  *(float4*)(up1 + ((size_t)n0 << 8) + d * 4) = make_float4(u00, u01, u02, u03);
  if (ok1) {
    res[((size_t)n1 << 6) + d] = r1;
    *(float4*)(up1 + ((size_t)n1 << 8) + d * 4) = make_float4(u10, u11, u12, u13);
  }
}

// ---------------------------------------------------------------- node kernel 2
__global__ __launch_bounds__(256) void k_node2(const float* __restrict__ agg1,
                                               const float* __restrict__ ld1,
                                               const float* __restrict__ pw1,
                                               const float* __restrict__ res,
                                               const float* __restrict__ mlp_w1,
                                               const float* __restrict__ mlp_w2,
                                               const int* __restrict__ species,
                                               const int* __restrict__ nsort,
                                               float* __restrict__ out) {
  __shared__ float __attribute__((aligned(16))) sm[4][2][1024];  // 32 KB
  __shared__ float sq[4][2][64];
  __shared__ float sf[4][2][64];
  int wave = threadIdx.x >> 6, d = threadIdx.x & 63;
  int i0 = blockIdx.x * 8 + wave * 2;
  int n0 = nsort[i0], n1 = nsort[i0 + 1];
  if (n0 < 0) return;
  bool ok1 = (n1 >= 0);
  int nv1 = ok1 ? n1 : n0;
  int sp = species[n0];
  float* A0 = sm[wave][0];
  float* A1 = sm[wave][1];

  {
    const float* ag = agg1 + ((size_t)n0 << 10);
    float v[16];
#pragma unroll
    for (int m = 0; m < 16; m++) v[m] = ag[(m << 6) + d] * 0.0625f;
#pragma unroll
    for (int g = 0; g < 4; g++)
      *(float4*)(A0 + d * 16 + g * 4) = make_float4(v[g*4], v[g*4+1], v[g*4+2], v[g*4+3]);
  }
  {
    const float* ag = agg1 + ((size_t)nv1 << 10);
    float v[16];
#pragma unroll
    for (int m = 0; m < 16; m++) v[m] = ag[(m << 6) + d] * 0.0625f;
#pragma unroll
    for (int g = 0; g < 4; g++)
      *(float4*)(A1 + d * 16 + g * 4) = make_float4(v[g*4], v[g*4+1], v[g*4+2], v[g*4+3]);
  }

  // g = agg @ ld1[l]
  float g0[16], g1[16];
#pragma unroll
  for (int m = 0; m < 16; m++) { g0[m] = 0.0f; g1[m] = 0.0f; }
#pragma unroll 4
  for (int c = 0; c < 64; c++) {
    float w0 = ld1[c * 64 + d];
    float w1 = ld1[4096 + c * 64 + d];
    float w2 = ld1[8192 + c * 64 + d];
    float w3 = ld1[12288 + c * 64 + d];
    fma16(g0, A0, c, w0, w1, w2, w3);
    fma16(g1, A1, c, w0, w1, w2, w3);
  }
  float inv0 = g0[0], inv1 = g1[0];
#pragma unroll
  for (int m = 1; m < 16; m++) { inv0 += g0[m] * g0[m]; inv1 += g1[m] * g1[m]; }
  sq[wave][0][d] = inv0 + inv0 * inv0;
  sq[wave][1][d] = inv1 + inv1 * inv1;

  // f2 = q @ prod_w1[sp] + res
  float a0 = res[((size_t)n0 << 6) + d];
  float a1 = res[((size_t)nv1 << 6) + d];
  const float* Wp = pw1 + ((size_t)sp << 12);
#pragma unroll 4
  for (int c = 0; c < 64; c++) {
    float w = Wp[c * 64 + d];
    a0 += sq[wave][0][c] * w;
    a1 += sq[wave][1][c] * w;
  }
  sf[wave][0][d] = a0;
  sf[wave][1][d] = a1;

  float val0 = 0.0f, val1 = 0.0f;
  if (d < 32) {
    float h0 = 0.0f, h1 = 0.0f;
#pragma unroll 4
    for (int c = 0; c < 64; c++) {
      float w = mlp_w1[c * 32 + d];
      h0 += sf[wave][0][c] * w;
      h1 += sf[wave][1][c] * w;
    }
    float w2 = mlp_w2[d];
    val0 = silu_f(h0) * w2;
    val1 = silu_f(h1) * w2;
  }
  val0 = reduce64(val0);
  val1 = reduce64(val1);
  if (d == 0) {
    out[2 * n0 + 1] = val0;
    if (ok1) out[2 * n1 + 1] = val1;
  }
}

// ---------------------------------------------------------------- launch
extern "C" void kernel_launch(void* const* d_in, const int* in_sizes, int n_in,
                              void* d_out, int out_size, void* d_ws, size_t ws_size,
                              hipStream_t stream) {
  const float* ev      = (const float*)d_in[0];
  const float* embed   = (const float*)d_in[1];
  const float* rw1     = (const float*)d_in[2];
  const float* rw2     = (const float*)d_in[3];
  const float* lu0     = (const float*)d_in[4];
  const float* lu1     = (const float*)d_in[5];
  const float* ld      = (const float*)d_in[6];
  const float* sel_w   = (const float*)d_in[7];
  const float* pw0     = (const float*)d_in[8];
  const float* pw1     = (const float*)d_in[9];
  const float* res_w   = (const float*)d_in[10];
  const float* read0   = (const float*)d_in[11];
  const float* mlp_w1  = (const float*)d_in[12];
  const float* mlp_w2  = (const float*)d_in[13];
  const int* species   = (const int*)d_in[14];
  const int* senders   = (const int*)d_in[15];
  const int* receivers = (const int*)d_in[16];
  float* out = (float*)d_out;

  int N = in_sizes[14];
  int E = in_sizes[15];
  int EPAD = ((E + 63) / 64) * 64;
  int NP = ((N + 70 + 7) / 8) * 8;   // species groups padded to 8; -1 fill

  float* ws = (float*)d_ws;
  size_t o = 0;
  float* agg  = ws + o;  o += (size_t)N * 1024;
  float* up0  = ws + o;  o += (size_t)N * 64;
  float* up1  = ws + o;  o += (size_t)N * 256;    // layout [n][c][4]
  float* resb = ws + o;  o += (size_t)N * 64;
  _Float16* b1t  = (_Float16*)(ws + o); o += 8192;
  _Float16* b2t  = (_Float16*)(ws + o); o += 12288;
  _Float16* hid0 = (_Float16*)(ws + o); o += (size_t)EPAD * 32;
  _Float16* hid1 = (_Float16*)(ws + o); o += (size_t)EPAD * 32;
  float* Ysort = ws + o; o += (size_t)EPAD * 16;
  int* row_start = (int*)(ws + o); o += (size_t)N + 1;
  int* cursor    = (int*)(ws + o); o += (size_t)N;
  int* scnt      = (int*)(ws + o); o += 16;
  int* perm      = (int*)(ws + o); o += (size_t)E;
  int* rsort     = (int*)(ws + o); o += (size_t)EPAD;
  int* ssort     = (int*)(ws + o); o += (size_t)EPAD;
  int* nsort     = (int*)(ws + o); o += (size_t)NP;

  hipMemsetAsync(agg, 0, (size_t)N * 1024 * sizeof(float), stream);
  hipMemsetAsync(cursor, 0, ((size_t)N + 16) * sizeof(int), stream);  // cursor + scnt
  hipMemsetAsync(nsort, 0xFF, (size_t)NP * sizeof(int), stream);      // -1 fill

  // CSR build (edges, shared by both interactions)
  k_hist<<<(E + 255) / 256, 256, 0, stream>>>(receivers, cursor, E);
  k_scan<<<1, 256, 0, stream>>>(cursor, row_start, cursor, N);
  k_scatter<<<(E + 255) / 256, 256, 0, stream>>>(receivers, senders, cursor,
                                                 perm, rsort, ssort, E);

  // species sort (nodes)
  k_nhist<<<(N + 255) / 256, 256, 0, stream>>>(species, scnt, N);
  k_nscan<<<1, 1, 0, stream>>>(scnt);
  k_nscatter<<<(N + 255) / 256, 256, 0, stream>>>(species, scnt, nsort, N);

  k_pack<<<160, 256, 0, stream>>>(rw2, b1t, b2t);
  k_up0<<<(N + 3) / 4, 256, 0, stream>>>(embed, lu0, species, up0, N);
  k_geom<<<EPAD / 4, 256, 0, stream>>>(ev, rw1, perm, hid0, hid1, Ysort,
                                       rsort, ssort, E, EPAD);

  int fblocks = EPAD / 64;
  k_fagg1<<<fblocks, 256, 0, stream>>>(hid0, b1t, Ysort, up0, ssort, rsort, agg, E);
  k_node1<<<NP / 8, 256, 0, stream>>>(agg, ld, sel_w, pw0, res_w, lu1, read0,
                                      species, nsort, out, resb, up1);
  k_fagg2<<<fblocks, 256, 0, stream>>>(hid1, b2t, Ysort, up1, ssort, rsort, agg, E);
  k_node2<<<NP / 8, 256, 0, stream>>>(agg, ld + 16384, pw1, resb, mlp_w1, mlp_w2,
                                      species, nsort, out);
}